// Round 8
// baseline (534.542 us; speedup 1.0000x reference)
//
#include <hip/hip_runtime.h>
#include <hip/hip_bf16.h>

typedef __bf16 bf16x8 __attribute__((ext_vector_type(8)));
typedef __bf16 bf16x4 __attribute__((ext_vector_type(4)));
typedef float  f32x4  __attribute__((ext_vector_type(4)));

#define KNB  9
#define BM   32    // faces per block (24 KiB LDS -> 6 blocks/CU)
#define ROWB 768   // bytes per LDS row: 384 bf16 ([g0|g1|g2], 128 cols each)

// ---------------- x fp32 -> bf16 table (d_ws) ----------------------------------
__global__ __launch_bounds__(256) void cvt_bf16(const float* __restrict__ x,
                                                __bf16* __restrict__ t) {
  const size_t i = ((size_t)blockIdx.x * 256 + threadIdx.x) * 8;
  f32x4 a = __builtin_nontemporal_load((const f32x4*)(x + i));      // x: read once
  f32x4 b = __builtin_nontemporal_load((const f32x4*)(x + i + 4));
  bf16x8 o;
  o[0]=(__bf16)a[0]; o[1]=(__bf16)a[1]; o[2]=(__bf16)a[2]; o[3]=(__bf16)a[3];
  o[4]=(__bf16)b[0]; o[5]=(__bf16)b[1]; o[6]=(__bf16)b[2]; o[7]=(__bf16)b[3];
  *(bf16x8*)(t + i) = o;                     // full-line cached store; table stays in L3
}

// ---------------- fused gather + symmetric fold + MFMA -------------------------
// BF16TAB=1: gather bf16 rows (256B) from table; else fp32 rows (512B) from x.
template<bool BF16TAB>
__global__ __launch_bounds__(256, 6)
void sfc_main(const void* __restrict__ xtab,
              const float* __restrict__ w0,
              const float* __restrict__ w1,
              const float* __restrict__ w2,
              const float* __restrict__ bias,
              const int*   __restrict__ fn,
              float* __restrict__ out,
              int n_real)
{
  __shared__ char Gs[BM * ROWB];          // 24 KiB; reused as 16 KiB fp32 out-tile
  const int tid = (int)threadIdx.x;
  const int l   = tid & 63;
  const int w   = tid >> 6;               // wave id 0..3
  const int m0  = (int)blockIdx.x * BM;
  const int g   = l >> 4;                 // 16-lane group 0..3 (4 faces/wave in flight)
  const int lc  = l & 15;

  // ---------- gather phase: wave covers faces w*8 .. w*8+7, 4 at a time ---------
  #pragma unroll
  for (int p = 0; p < 2; ++p) {
    const int f    = w * 8 + p * 4 + g;
    const int base = (m0 + f) * KNB;
    int idx[KNB];
    #pragma unroll
    for (int k = 0; k < KNB; ++k) idx[k] = fn[base + k];   // plain cached loads

    char* rb = Gs + f * ROWB;
    const unsigned swz = (unsigned)((f & 7) << 4);   // XOR bits 4-6

    if constexpr (BF16TAB) {
      const __bf16* xt = (const __bf16*)xtab;
      bf16x8 v[KNB];
      #pragma unroll
      for (int k = 0; k < KNB; ++k) {
        bf16x8 z;
        #pragma unroll
        for (int j = 0; j < 8; ++j) z[j] = (__bf16)0.f;
        v[k] = z;
        if (idx[k] < n_real)
          v[k] = *(const bf16x8*)(xt + ((size_t)idx[k] << 7) + (lc << 3));
      }
      float a1[8], a2[8];
      #pragma unroll
      for (int j = 0; j < 8; ++j) {
        a1[j] = (float)v[1][j] + (float)v[3][j] + (float)v[5][j] + (float)v[7][j];
        a2[j] = (float)v[2][j] + (float)v[4][j] + (float)v[6][j] + (float)v[8][j];
      }
      bf16x8 c1, c2;
      #pragma unroll
      for (int j = 0; j < 8; ++j) { c1[j] = (__bf16)a1[j]; c2[j] = (__bf16)a2[j]; }
      const unsigned o = (unsigned)(lc << 4);
      *(bf16x8*)(rb + ((o        ) ^ swz)) = v[0];
      *(bf16x8*)(rb + ((o + 256u ) ^ swz)) = c1;
      *(bf16x8*)(rb + ((o + 512u ) ^ swz)) = c2;
    } else {
      const float* x = (const float*)xtab;
      f32x4 a0[2], a1[2], a2[2];
      #pragma unroll
      for (int h = 0; h < 2; ++h) { a0[h] = {0,0,0,0}; a1[h] = a0[h]; a2[h] = a0[h]; }
      #pragma unroll
      for (int k = 0; k < KNB; ++k) {
        #pragma unroll
        for (int h = 0; h < 2; ++h) {
          f32x4 v = {0,0,0,0};
          if (idx[k] < n_real)
            v = *(const f32x4*)(x + ((size_t)idx[k] << 7) + h * 64 + (lc << 2));
          if (k == 0)      a0[h] = v;
          else if (k & 1)  a1[h] += v;
          else             a2[h] += v;
        }
      }
      #pragma unroll
      for (int h = 0; h < 2; ++h) {
        const unsigned o = (unsigned)(h * 128 + (lc << 3));
        bf16x4 b0, b1, b2;
        #pragma unroll
        for (int j = 0; j < 4; ++j) {
          b0[j]=(__bf16)a0[h][j]; b1[j]=(__bf16)a1[h][j]; b2[j]=(__bf16)a2[h][j];
        }
        *(bf16x4*)(rb + ((o        ) ^ swz)) = b0;
        *(bf16x4*)(rb + ((o + 256u ) ^ swz)) = b1;
        *(bf16x4*)(rb + ((o + 512u ) ^ swz)) = b2;
      }
    }
  }
  __syncthreads();

  // ---------- B-operand load after barrier (short live range) -------------------
  // B[k][o], k = gg*128+c: lane -> col o0+nt*16+(l&15), k = ks*32+(l>>4)*8+j.
  const int o0 = w * 32;
  bf16x8 bfr[12][2];
  #pragma unroll
  for (int ks = 0; ks < 12; ++ks) {
    const int k = ks * 32 + ((l >> 4) << 3);
    const int gg = k >> 7;
    const int c  = k & 127;
    const float* wsel = (gg == 0) ? w0 : ((gg == 1) ? w1 : w2);
    #pragma unroll
    for (int nt = 0; nt < 2; ++nt) {
      const int o = o0 + nt * 16 + (l & 15);
      const float* wp = wsel + o * 128 + c;
      f32x4 lo = *(const f32x4*)(wp);
      f32x4 hi = *(const f32x4*)(wp + 4);
      bf16x8 t;
      t[0]=(__bf16)lo[0]; t[1]=(__bf16)lo[1]; t[2]=(__bf16)lo[2]; t[3]=(__bf16)lo[3];
      t[4]=(__bf16)hi[0]; t[5]=(__bf16)hi[1]; t[6]=(__bf16)hi[2]; t[7]=(__bf16)hi[3];
      bfr[ks][nt] = t;
    }
  }

  // ---------- MFMA: per wave C(32x32) = G(32x384) x W(384x32) -------------------
  f32x4 acc[2][2] = {};
  __builtin_amdgcn_s_setprio(1);
  #pragma unroll
  for (int ks = 0; ks < 12; ++ks) {
    bf16x8 af[2];
    #pragma unroll
    for (int mt = 0; mt < 2; ++mt) {
      const unsigned row = (unsigned)(mt * 16 + (l & 15));
      unsigned off = row * ROWB + (unsigned)((ks * 32 + ((l >> 4) << 3)) << 1);
      off ^= (unsigned)((l & 7) << 4);               // row&7 == l&7 here
      af[mt] = *(const bf16x8*)(Gs + off);
    }
    #pragma unroll
    for (int mt = 0; mt < 2; ++mt)
      #pragma unroll
      for (int nt = 0; nt < 2; ++nt)
        acc[mt][nt] = __builtin_amdgcn_mfma_f32_16x16x32_bf16(
            af[mt], bfr[ks][nt], acc[mt][nt], 0, 0, 0);
  }
  __builtin_amdgcn_s_setprio(0);

  // ---------- epilogue: LDS-staged, full-line coalesced out-stores ---------------
  // Stage acc(+bias) into Gs as a 32x128 fp32 tile (XOR-swizzled: banks alias
  // at most 2-way = free), then stream full 512B rows with f32x4 stores so every
  // 128B line is written by ONE instruction (kills partial-line write RMW).
  __syncthreads();                                   // all MFMA reads of Gs done
  const float bv0 = bias[o0 +      (l & 15)];
  const float bv1 = bias[o0 + 16 + (l & 15)];
  #pragma unroll
  for (int mt = 0; mt < 2; ++mt) {
    #pragma unroll
    for (int r = 0; r < 4; ++r) {
      const int row = mt * 16 + ((l >> 4) << 2) + r;         // D: row=(lane>>4)*4+reg
      const unsigned sw = (unsigned)((row & 7) << 4);
      const unsigned b0 = ((unsigned)(row * 512 + (o0      + (l & 15)) * 4)) ^ sw;
      const unsigned b1 = ((unsigned)(row * 512 + (o0 + 16 + (l & 15)) * 4)) ^ sw;
      *(float*)(Gs + b0) = acc[mt][0][r] + bv0;              // D: col=lane&15
      *(float*)(Gs + b1) = acc[mt][1][r] + bv1;
    }
  }
  __syncthreads();
  #pragma unroll
  for (int i = 0; i < 4; ++i) {
    const int flat = i * 256 + tid;                  // units of 16B
    const int row  = flat >> 5;                      // 32 x 16B per 512B row
    const int c16  = flat & 31;
    const unsigned lb = ((unsigned)(row * 512 + c16 * 16)) ^ ((unsigned)((row & 7) << 4));
    f32x4 v = *(const f32x4*)(Gs + lb);
    *(f32x4*)(out + (size_t)(m0 + row) * 128 + c16 * 4) = v;
  }
}

extern "C" void kernel_launch(void* const* d_in, const int* in_sizes, int n_in,
                              void* d_out, int out_size, void* d_ws, size_t ws_size,
                              hipStream_t stream) {
  const float* x    = (const float*)d_in[0];
  const float* w0   = (const float*)d_in[1];
  const float* w1   = (const float*)d_in[2];
  const float* w2   = (const float*)d_in[3];
  const float* bias = (const float*)d_in[4];
  const int*   fn   = (const int*)d_in[5];
  float* out = (float*)d_out;

  const int n_real = in_sizes[0] / 128;           // 262144
  const int grid   = n_real / BM;                 // 8192 blocks, 256 thr (4 waves)
  const size_t need = (size_t)n_real * 128 * sizeof(__bf16);   // 67 MB

  if (ws_size >= need) {
    __bf16* xtab = (__bf16*)d_ws;
    const int cgrid = (n_real * 128) / (256 * 8); // 16384
    cvt_bf16<<<cgrid, 256, 0, stream>>>(x, xtab);
    sfc_main<true><<<grid, 256, 0, stream>>>(xtab, w0, w1, w2, bias, fn, out, n_real);
  } else {
    sfc_main<false><<<grid, 256, 0, stream>>>(x, w0, w1, w2, bias, fn, out, n_real);
  }
}

// Round 10
// 371.323 us; speedup vs baseline: 1.4396x; 1.4396x over previous
//
#include <hip/hip_runtime.h>
#include <hip/hip_bf16.h>

typedef __bf16 bf16x8 __attribute__((ext_vector_type(8)));
typedef __bf16 bf16x4 __attribute__((ext_vector_type(4)));
typedef float  f32x4  __attribute__((ext_vector_type(4)));

#define KNB  9
#define BM   64    // faces per block; 48 KiB LDS -> 3 blocks/CU (round-4 footprint)
#define ROWB 768   // bytes per LDS row: 384 bf16 ([g0|g1|g2], 128 cols each)

// ---------------- x fp32 -> bf16 table (d_ws) ----------------------------------
__global__ __launch_bounds__(256) void cvt_bf16(const float* __restrict__ x,
                                                __bf16* __restrict__ t) {
  const size_t i = ((size_t)blockIdx.x * 256 + threadIdx.x) * 8;
  f32x4 a = __builtin_nontemporal_load((const f32x4*)(x + i));      // x: read once
  f32x4 b = __builtin_nontemporal_load((const f32x4*)(x + i + 4));
  bf16x8 o;
  o[0]=(__bf16)a[0]; o[1]=(__bf16)a[1]; o[2]=(__bf16)a[2]; o[3]=(__bf16)a[3];
  o[4]=(__bf16)b[0]; o[5]=(__bf16)b[1]; o[6]=(__bf16)b[2]; o[7]=(__bf16)b[3];
  *(bf16x8*)(t + i) = o;                     // cached store; table stays in L3
}

// ---------------- fused gather + symmetric fold + MFMA -------------------------
// 512 threads = 8 waves. Per-wave: gather 8 faces, compute C(64x16) slice.
// BF16TAB=1: gather bf16 rows (256B) from table; else fp32 rows (512B) from x.
template<bool BF16TAB>
__global__ __launch_bounds__(512, 6)
void sfc_main(const void* __restrict__ xtab,
              const float* __restrict__ w0,
              const float* __restrict__ w1,
              const float* __restrict__ w2,
              const float* __restrict__ bias,
              const int*   __restrict__ fn,
              float* __restrict__ out,
              int n_real)
{
  __shared__ char Gs[BM * ROWB];          // 48 KiB, XOR-swizzled bf16 G-tile
  const int tid = (int)threadIdx.x;
  const int l   = tid & 63;
  const int w   = tid >> 6;               // wave id 0..7
  const int m0  = (int)blockIdx.x * BM;
  const int g   = l >> 4;                 // 16-lane group 0..3 (4 faces/wave in flight)
  const int lc  = l & 15;

  // ---------- gather phase: wave covers faces w*8 .. w*8+7, 4 at a time ---------
  #pragma unroll
  for (int p = 0; p < 2; ++p) {
    const int f    = w * 8 + p * 4 + g;
    const int base = (m0 + f) * KNB;
    int idx[KNB];
    #pragma unroll
    for (int k = 0; k < KNB; ++k) idx[k] = fn[base + k];   // plain cached loads

    char* rb = Gs + f * ROWB;
    const unsigned swz = (unsigned)((f & 7) << 4);   // XOR bits 4-6

    if constexpr (BF16TAB) {
      const __bf16* xt = (const __bf16*)xtab;
      bf16x8 v[KNB];
      #pragma unroll
      for (int k = 0; k < KNB; ++k) {
        bf16x8 z;
        #pragma unroll
        for (int j = 0; j < 8; ++j) z[j] = (__bf16)0.f;
        v[k] = z;
        if (idx[k] < n_real)
          v[k] = *(const bf16x8*)(xt + ((size_t)idx[k] << 7) + (lc << 3));
      }
      float a1[8], a2[8];
      #pragma unroll
      for (int j = 0; j < 8; ++j) {
        a1[j] = (float)v[1][j] + (float)v[3][j] + (float)v[5][j] + (float)v[7][j];
        a2[j] = (float)v[2][j] + (float)v[4][j] + (float)v[6][j] + (float)v[8][j];
      }
      bf16x8 c1, c2;
      #pragma unroll
      for (int j = 0; j < 8; ++j) { c1[j] = (__bf16)a1[j]; c2[j] = (__bf16)a2[j]; }
      const unsigned o = (unsigned)(lc << 4);
      *(bf16x8*)(rb + ((o        ) ^ swz)) = v[0];
      *(bf16x8*)(rb + ((o + 256u ) ^ swz)) = c1;
      *(bf16x8*)(rb + ((o + 512u ) ^ swz)) = c2;
    } else {
      const float* x = (const float*)xtab;
      f32x4 a0[2], a1[2], a2[2];
      #pragma unroll
      for (int h = 0; h < 2; ++h) { a0[h] = {0,0,0,0}; a1[h] = a0[h]; a2[h] = a0[h]; }
      #pragma unroll
      for (int k = 0; k < KNB; ++k) {
        #pragma unroll
        for (int h = 0; h < 2; ++h) {
          f32x4 v = {0,0,0,0};
          if (idx[k] < n_real)
            v = *(const f32x4*)(x + ((size_t)idx[k] << 7) + h * 64 + (lc << 2));
          if (k == 0)      a0[h] = v;
          else if (k & 1)  a1[h] += v;
          else             a2[h] += v;
        }
      }
      #pragma unroll
      for (int h = 0; h < 2; ++h) {
        const unsigned o = (unsigned)(h * 128 + (lc << 3));
        bf16x4 b0, b1, b2;
        #pragma unroll
        for (int j = 0; j < 4; ++j) {
          b0[j]=(__bf16)a0[h][j]; b1[j]=(__bf16)a1[h][j]; b2[j]=(__bf16)a2[h][j];
        }
        *(bf16x4*)(rb + ((o        ) ^ swz)) = b0;
        *(bf16x4*)(rb + ((o + 256u ) ^ swz)) = b1;
        *(bf16x4*)(rb + ((o + 512u ) ^ swz)) = b2;
      }
    }
  }
  __syncthreads();

  // ---------- MFMA: per wave C(64x16) = G(64x384) x W(384x16) -------------------
  // B-fragment loaded INSIDE the k-loop (4 VGPRs live; weights are 192KB,
  // L2-resident broadcast) to keep register demand < the bounds(512,6) cap.
  const int o0 = w * 16;
  const int oc = o0 + (l & 15);            // this lane's output column
  f32x4 acc[4] = {};
  __builtin_amdgcn_s_setprio(1);
  #pragma unroll
  for (int ks = 0; ks < 12; ++ks) {
    // B frag: k = ks*32 + (l>>4)*8 + j, col = oc
    const int k  = ks * 32 + ((l >> 4) << 3);
    const int gg = k >> 7;
    const int c  = k & 127;
    const float* wsel = (gg == 0) ? w0 : ((gg == 1) ? w1 : w2);
    const float* wp = wsel + oc * 128 + c;
    f32x4 blo = *(const f32x4*)(wp);
    f32x4 bhi = *(const f32x4*)(wp + 4);
    bf16x8 bq;
    bq[0]=(__bf16)blo[0]; bq[1]=(__bf16)blo[1]; bq[2]=(__bf16)blo[2]; bq[3]=(__bf16)blo[3];
    bq[4]=(__bf16)bhi[0]; bq[5]=(__bf16)bhi[1]; bq[6]=(__bf16)bhi[2]; bq[7]=(__bf16)bhi[3];

    bf16x8 af[4];
    #pragma unroll
    for (int mt = 0; mt < 4; ++mt) {
      const unsigned row = (unsigned)(mt * 16 + (l & 15));
      unsigned off = row * ROWB + (unsigned)(k << 1);
      off ^= (unsigned)((l & 7) << 4);               // row&7 == l&7 here
      af[mt] = *(const bf16x8*)(Gs + off);
    }
    #pragma unroll
    for (int mt = 0; mt < 4; ++mt)
      acc[mt] = __builtin_amdgcn_mfma_f32_16x16x32_bf16(af[mt], bq, acc[mt], 0, 0, 0);
  }
  __builtin_amdgcn_s_setprio(0);

  // ---------- epilogue: + bias, direct fp32 stores (round-4 proven) --------------
  const float bv = bias[oc];
  #pragma unroll
  for (int mt = 0; mt < 4; ++mt) {
    #pragma unroll
    for (int r = 0; r < 4; ++r) {
      const int m = m0 + mt * 16 + ((l >> 4) << 2) + r;   // D: row=(lane>>4)*4+reg
      out[(size_t)m * 128 + oc] = acc[mt][r] + bv;        // D: col=lane&15
    }
  }
}

extern "C" void kernel_launch(void* const* d_in, const int* in_sizes, int n_in,
                              void* d_out, int out_size, void* d_ws, size_t ws_size,
                              hipStream_t stream) {
  const float* x    = (const float*)d_in[0];
  const float* w0   = (const float*)d_in[1];
  const float* w1   = (const float*)d_in[2];
  const float* w2   = (const float*)d_in[3];
  const float* bias = (const float*)d_in[4];
  const int*   fn   = (const int*)d_in[5];
  float* out = (float*)d_out;

  const int n_real = in_sizes[0] / 128;           // 262144
  const int grid   = n_real / BM;                 // 4096 blocks, 512 thr (8 waves)
  const size_t need = (size_t)n_real * 128 * sizeof(__bf16);   // 67 MB

  if (ws_size >= need) {
    __bf16* xtab = (__bf16*)d_ws;
    const int cgrid = (n_real * 128) / (256 * 8); // 16384
    cvt_bf16<<<cgrid, 256, 0, stream>>>(x, xtab);
    sfc_main<true><<<grid, 512, 0, stream>>>(xtab, w0, w1, w2, bias, fn, out, n_real);
  } else {
    sfc_main<false><<<grid, 512, 0, stream>>>(x, w0, w1, w2, bias, fn, out, n_real);
  }
}

// Round 13
// 368.985 us; speedup vs baseline: 1.4487x; 1.0063x over previous
//
#include <hip/hip_runtime.h>
#include <hip/hip_bf16.h>

typedef __bf16 bf16x8 __attribute__((ext_vector_type(8)));
typedef __bf16 bf16x4 __attribute__((ext_vector_type(4)));
typedef float  f32x4  __attribute__((ext_vector_type(4)));

#define KNB  9
#define BM   64    // faces per block; 48 KiB LDS -> 3 blocks/CU
#define ROWB 768   // bytes per LDS row: 384 bf16 ([g0|g1|g2], 128 cols each)

// ---------------- x fp32 -> bf16 table (d_ws) ----------------------------------
__global__ __launch_bounds__(256) void cvt_bf16(const float* __restrict__ x,
                                                __bf16* __restrict__ t) {
  const size_t i = ((size_t)blockIdx.x * 256 + threadIdx.x) * 8;
  f32x4 a = __builtin_nontemporal_load((const f32x4*)(x + i));      // x: read once
  f32x4 b = __builtin_nontemporal_load((const f32x4*)(x + i + 4));
  bf16x8 o;
  o[0]=(__bf16)a[0]; o[1]=(__bf16)a[1]; o[2]=(__bf16)a[2]; o[3]=(__bf16)a[3];
  o[4]=(__bf16)b[0]; o[5]=(__bf16)b[1]; o[6]=(__bf16)b[2]; o[7]=(__bf16)b[3];
  *(bf16x8*)(t + i) = o;                     // cached store; table stays in L3
}

// ---------------- fused gather + symmetric fold + MFMA -------------------------
// 512 threads = 8 waves. Per-wave: gather 8 faces, compute C(64x16) slice.
// Epilogue: LDS-staged full-line nontemporal out-stores (keep L3 for the table).
template<bool BF16TAB>
__global__ __launch_bounds__(512, 6)
void sfc_main(const void* __restrict__ xtab,
              const float* __restrict__ w0,
              const float* __restrict__ w1,
              const float* __restrict__ w2,
              const float* __restrict__ bias,
              const int*   __restrict__ fn,
              float* __restrict__ out,
              int n_real)
{
  __shared__ char Gs[BM * ROWB];          // 48 KiB; reused as 32 KiB fp32 out-tile
  const int tid = (int)threadIdx.x;
  const int l   = tid & 63;
  const int w   = tid >> 6;               // wave id 0..7
  const int m0  = (int)blockIdx.x * BM;
  const int g   = l >> 4;                 // 16-lane group 0..3 (4 faces/wave in flight)
  const int lc  = l & 15;

  // ---------- gather phase: wave covers faces w*8 .. w*8+7, 4 at a time ---------
  #pragma unroll
  for (int p = 0; p < 2; ++p) {
    const int f    = w * 8 + p * 4 + g;
    const int base = (m0 + f) * KNB;
    int idx[KNB];
    #pragma unroll
    for (int k = 0; k < KNB; ++k) idx[k] = fn[base + k];   // plain cached loads

    char* rb = Gs + f * ROWB;
    const unsigned swz = (unsigned)((f & 7) << 4);   // XOR bits 4-6

    if constexpr (BF16TAB) {
      const __bf16* xt = (const __bf16*)xtab;
      bf16x8 v[KNB];
      #pragma unroll
      for (int k = 0; k < KNB; ++k) {
        bf16x8 z;
        #pragma unroll
        for (int j = 0; j < 8; ++j) z[j] = (__bf16)0.f;
        v[k] = z;
        if (idx[k] < n_real)
          v[k] = *(const bf16x8*)(xt + ((size_t)idx[k] << 7) + (lc << 3));
      }
      float a1[8], a2[8];
      #pragma unroll
      for (int j = 0; j < 8; ++j) {
        a1[j] = (float)v[1][j] + (float)v[3][j] + (float)v[5][j] + (float)v[7][j];
        a2[j] = (float)v[2][j] + (float)v[4][j] + (float)v[6][j] + (float)v[8][j];
      }
      bf16x8 c1, c2;
      #pragma unroll
      for (int j = 0; j < 8; ++j) { c1[j] = (__bf16)a1[j]; c2[j] = (__bf16)a2[j]; }
      const unsigned o = (unsigned)(lc << 4);
      *(bf16x8*)(rb + ((o        ) ^ swz)) = v[0];
      *(bf16x8*)(rb + ((o + 256u ) ^ swz)) = c1;
      *(bf16x8*)(rb + ((o + 512u ) ^ swz)) = c2;
    } else {
      const float* x = (const float*)xtab;
      f32x4 a0[2], a1[2], a2[2];
      #pragma unroll
      for (int h = 0; h < 2; ++h) { a0[h] = {0,0,0,0}; a1[h] = a0[h]; a2[h] = a0[h]; }
      #pragma unroll
      for (int k = 0; k < KNB; ++k) {
        #pragma unroll
        for (int h = 0; h < 2; ++h) {
          f32x4 v = {0,0,0,0};
          if (idx[k] < n_real)
            v = *(const f32x4*)(x + ((size_t)idx[k] << 7) + h * 64 + (lc << 2));
          if (k == 0)      a0[h] = v;
          else if (k & 1)  a1[h] += v;
          else             a2[h] += v;
        }
      }
      #pragma unroll
      for (int h = 0; h < 2; ++h) {
        const unsigned o = (unsigned)(h * 128 + (lc << 3));
        bf16x4 b0, b1, b2;
        #pragma unroll
        for (int j = 0; j < 4; ++j) {
          b0[j]=(__bf16)a0[h][j]; b1[j]=(__bf16)a1[h][j]; b2[j]=(__bf16)a2[h][j];
        }
        *(bf16x4*)(rb + ((o        ) ^ swz)) = b0;
        *(bf16x4*)(rb + ((o + 256u ) ^ swz)) = b1;
        *(bf16x4*)(rb + ((o + 512u ) ^ swz)) = b2;
      }
    }
  }
  __syncthreads();

  // ---------- MFMA: per wave C(64x16) = G(64x384) x W(384x16) -------------------
  const int o0 = w * 16;
  const int oc = o0 + (l & 15);            // this lane's output column
  f32x4 acc[4] = {};
  __builtin_amdgcn_s_setprio(1);
  #pragma unroll
  for (int ks = 0; ks < 12; ++ks) {
    const int k  = ks * 32 + ((l >> 4) << 3);
    const int gg = k >> 7;
    const int c  = k & 127;
    const float* wsel = (gg == 0) ? w0 : ((gg == 1) ? w1 : w2);
    const float* wp = wsel + oc * 128 + c;
    f32x4 blo = *(const f32x4*)(wp);
    f32x4 bhi = *(const f32x4*)(wp + 4);
    bf16x8 bq;
    bq[0]=(__bf16)blo[0]; bq[1]=(__bf16)blo[1]; bq[2]=(__bf16)blo[2]; bq[3]=(__bf16)blo[3];
    bq[4]=(__bf16)bhi[0]; bq[5]=(__bf16)bhi[1]; bq[6]=(__bf16)bhi[2]; bq[7]=(__bf16)bhi[3];

    bf16x8 af[4];
    #pragma unroll
    for (int mt = 0; mt < 4; ++mt) {
      const unsigned row = (unsigned)(mt * 16 + (l & 15));
      unsigned off = row * ROWB + (unsigned)(k << 1);
      off ^= (unsigned)((l & 7) << 4);               // row&7 == l&7 here
      af[mt] = *(const bf16x8*)(Gs + off);
    }
    #pragma unroll
    for (int mt = 0; mt < 4; ++mt)
      acc[mt] = __builtin_amdgcn_mfma_f32_16x16x32_bf16(af[mt], bq, acc[mt], 0, 0, 0);
  }
  __builtin_amdgcn_s_setprio(0);

  // ---------- epilogue: LDS-staged, full-line NONTEMPORAL out-stores -------------
  // Stage acc(+bias) into Gs as 64x128 fp32 (swizzle ((row>>2)&3)<<5: writes
  // <=2-way bank alias = free, reads uniform), then stream full 512B rows with
  // f32x4 nt-stores: every 128B line written whole -> no RMW, and the out
  // stream does not evict the gather table from L2/L3.
  __syncthreads();                                   // all MFMA reads of Gs done
  const float bv = bias[oc];
  #pragma unroll
  for (int mt = 0; mt < 4; ++mt) {
    #pragma unroll
    for (int r = 0; r < 4; ++r) {
      const int row = mt * 16 + ((l >> 4) << 2) + r;       // D: row=(lane>>4)*4+reg
      const unsigned b = ((unsigned)(row * 512 + oc * 4)) ^
                         ((unsigned)(((row >> 2) & 3) << 5));
      *(float*)(Gs + b) = acc[mt][r] + bv;                 // D: col=lane&15
    }
  }
  __syncthreads();
  #pragma unroll
  for (int i = 0; i < 4; ++i) {
    const int flat = i * 512 + tid;                  // 2048 x 16B = 64 rows x 512B
    const int row  = flat >> 5;
    const int c16  = flat & 31;
    const unsigned lb = ((unsigned)(row * 512 + c16 * 16)) ^
                        ((unsigned)(((row >> 2) & 3) << 5));
    f32x4 v = *(const f32x4*)(Gs + lb);
    __builtin_nontemporal_store(v, (f32x4*)(out + (size_t)(m0 + row) * 128 + c16 * 4));
  }
}

extern "C" void kernel_launch(void* const* d_in, const int* in_sizes, int n_in,
                              void* d_out, int out_size, void* d_ws, size_t ws_size,
                              hipStream_t stream) {
  const float* x    = (const float*)d_in[0];
  const float* w0   = (const float*)d_in[1];
  const float* w1   = (const float*)d_in[2];
  const float* w2   = (const float*)d_in[3];
  const float* bias = (const float*)d_in[4];
  const int*   fn   = (const int*)d_in[5];
  float* out = (float*)d_out;

  const int n_real = in_sizes[0] / 128;           // 262144
  const int grid   = n_real / BM;                 // 4096 blocks, 512 thr (8 waves)
  const size_t need = (size_t)n_real * 128 * sizeof(__bf16);   // 67 MB

  if (ws_size >= need) {
    __bf16* xtab = (__bf16*)d_ws;
    const int cgrid = (n_real * 128) / (256 * 8); // 16384
    cvt_bf16<<<cgrid, 256, 0, stream>>>(x, xtab);
    sfc_main<true><<<grid, 512, 0, stream>>>(xtab, w0, w1, w2, bias, fn, out, n_real);
  } else {
    sfc_main<false><<<grid, 512, 0, stream>>>(x, w0, w1, w2, bias, fn, out, n_real);
  }
}

// Round 14
// 350.458 us; speedup vs baseline: 1.5253x; 1.0529x over previous
//
#include <hip/hip_runtime.h>
#include <hip/hip_bf16.h>

typedef __bf16 bf16x8 __attribute__((ext_vector_type(8)));
typedef __bf16 bf16x4 __attribute__((ext_vector_type(4)));
typedef float  f32x4  __attribute__((ext_vector_type(4)));

#define KNB  9
#define BM   64    // faces per block; 48 KiB LDS -> 3 blocks/CU
#define ROWB 768   // bytes per LDS row: 384 bf16 ([g0|g1|g2], 128 cols each)

// ---------------- x fp32 -> bf16 table (d_ws) ----------------------------------
__global__ __launch_bounds__(256) void cvt_bf16(const float* __restrict__ x,
                                                __bf16* __restrict__ t) {
  const size_t i = ((size_t)blockIdx.x * 256 + threadIdx.x) * 8;
  f32x4 a = __builtin_nontemporal_load((const f32x4*)(x + i));      // x: read once
  f32x4 b = __builtin_nontemporal_load((const f32x4*)(x + i + 4));
  bf16x8 o;
  o[0]=(__bf16)a[0]; o[1]=(__bf16)a[1]; o[2]=(__bf16)a[2]; o[3]=(__bf16)a[3];
  o[4]=(__bf16)b[0]; o[5]=(__bf16)b[1]; o[6]=(__bf16)b[2]; o[7]=(__bf16)b[3];
  *(bf16x8*)(t + i) = o;                     // cached store; table stays in L3
}

// ---------------- B-fragment pack + zero pad row --------------------------------
// bp[(w*12+ks)*64 + l][8]: lane l of wave w reads ONE contiguous 16B -> the wave's
// B fragment load is a single 1KB coalesced transaction instead of 16 scattered
// 16B segments (stride 512B) per instruction.
__global__ __launch_bounds__(256) void wpack(const float* __restrict__ w0,
                                             const float* __restrict__ w1,
                                             const float* __restrict__ w2,
                                             __bf16* __restrict__ bp,
                                             __bf16* __restrict__ tab,
                                             int n_real) {
  const int e = (int)blockIdx.x * 256 + (int)threadIdx.x;   // 6144 entries
  if (blockIdx.x == 0 && threadIdx.x < 16) {                // zero pad row n_real
    bf16x8 z;
    #pragma unroll
    for (int j = 0; j < 8; ++j) z[j] = (__bf16)0.f;
    *(bf16x8*)(tab + (size_t)n_real * 128 + threadIdx.x * 8) = z;
  }
  if (e >= 8 * 12 * 64) return;
  const int w  = e / 768;            // wave 0..7
  const int ks = (e / 64) % 12;      // k-step 0..11
  const int l  = e & 63;             // lane
  const int o  = w * 16 + (l & 15);
  const int kb = ks * 32 + ((l >> 4) << 3);
  const int gg = kb >> 7;
  const int c  = kb & 127;
  const float* ws = (gg == 0) ? w0 : ((gg == 1) ? w1 : w2);
  bf16x8 t;
  #pragma unroll
  for (int j = 0; j < 8; ++j) t[j] = (__bf16)ws[o * 128 + c + j];
  *(bf16x8*)(bp + (size_t)e * 8) = t;
}

// ---------------- fused gather + symmetric fold + MFMA -------------------------
// MODE 2: bf16 table + packed B + unconditional gather (zero pad row).
// MODE 1: bf16 table, round-13 behavior.  MODE 0: fp32 direct.
template<int MODE>
__global__ __launch_bounds__(512, 6)
void sfc_main(const void* __restrict__ xtab,
              const float* __restrict__ w0,
              const float* __restrict__ w1,
              const float* __restrict__ w2,
              const float* __restrict__ bias,
              const int*   __restrict__ fn,
              const __bf16* __restrict__ bp,
              float* __restrict__ out,
              int n_real)
{
  __shared__ char Gs[BM * ROWB];          // 48 KiB; reused as 32 KiB fp32 out-tile
  const int tid = (int)threadIdx.x;
  const int l   = tid & 63;
  const int w   = tid >> 6;               // wave id 0..7
  const int m0  = (int)blockIdx.x * BM;
  const int g   = l >> 4;                 // 16-lane group 0..3 (4 faces/wave in flight)
  const int lc  = l & 15;

  // ---------- gather phase: wave covers faces w*8 .. w*8+7, 4 at a time ---------
  #pragma unroll
  for (int p = 0; p < 2; ++p) {
    const int f    = w * 8 + p * 4 + g;
    const int base = (m0 + f) * KNB;
    int idx[KNB];
    #pragma unroll
    for (int k = 0; k < KNB; ++k) idx[k] = fn[base + k];   // plain cached loads

    char* rb = Gs + f * ROWB;
    const unsigned swz = (unsigned)((f & 7) << 4);   // XOR bits 4-6

    if constexpr (MODE >= 1) {
      const __bf16* xt = (const __bf16*)xtab;
      bf16x8 v[KNB];
      #pragma unroll
      for (int k = 0; k < KNB; ++k) {
        if constexpr (MODE == 2) {
          v[k] = *(const bf16x8*)(xt + ((size_t)idx[k] << 7) + (lc << 3));
        } else {
          bf16x8 z;
          #pragma unroll
          for (int j = 0; j < 8; ++j) z[j] = (__bf16)0.f;
          v[k] = z;
          if (idx[k] < n_real)
            v[k] = *(const bf16x8*)(xt + ((size_t)idx[k] << 7) + (lc << 3));
        }
      }
      float a1[8], a2[8];
      #pragma unroll
      for (int j = 0; j < 8; ++j) {
        a1[j] = (float)v[1][j] + (float)v[3][j] + (float)v[5][j] + (float)v[7][j];
        a2[j] = (float)v[2][j] + (float)v[4][j] + (float)v[6][j] + (float)v[8][j];
      }
      bf16x8 c1, c2;
      #pragma unroll
      for (int j = 0; j < 8; ++j) { c1[j] = (__bf16)a1[j]; c2[j] = (__bf16)a2[j]; }
      const unsigned o = (unsigned)(lc << 4);
      *(bf16x8*)(rb + ((o        ) ^ swz)) = v[0];
      *(bf16x8*)(rb + ((o + 256u ) ^ swz)) = c1;
      *(bf16x8*)(rb + ((o + 512u ) ^ swz)) = c2;
    } else {
      const float* x = (const float*)xtab;
      f32x4 a0[2], a1[2], a2[2];
      #pragma unroll
      for (int h = 0; h < 2; ++h) { a0[h] = {0,0,0,0}; a1[h] = a0[h]; a2[h] = a0[h]; }
      #pragma unroll
      for (int k = 0; k < KNB; ++k) {
        #pragma unroll
        for (int h = 0; h < 2; ++h) {
          f32x4 v = {0,0,0,0};
          if (idx[k] < n_real)
            v = *(const f32x4*)(x + ((size_t)idx[k] << 7) + h * 64 + (lc << 2));
          if (k == 0)      a0[h] = v;
          else if (k & 1)  a1[h] += v;
          else             a2[h] += v;
        }
      }
      #pragma unroll
      for (int h = 0; h < 2; ++h) {
        const unsigned o = (unsigned)(h * 128 + (lc << 3));
        bf16x4 b0, b1, b2;
        #pragma unroll
        for (int j = 0; j < 4; ++j) {
          b0[j]=(__bf16)a0[h][j]; b1[j]=(__bf16)a1[h][j]; b2[j]=(__bf16)a2[h][j];
        }
        *(bf16x4*)(rb + ((o        ) ^ swz)) = b0;
        *(bf16x4*)(rb + ((o + 256u ) ^ swz)) = b1;
        *(bf16x4*)(rb + ((o + 512u ) ^ swz)) = b2;
      }
    }
  }
  __syncthreads();

  // ---------- MFMA: per wave C(64x16) = G(64x384) x W(384x16) -------------------
  const int o0 = w * 16;
  const int oc = o0 + (l & 15);            // this lane's output column
  f32x4 acc[4] = {};
  __builtin_amdgcn_s_setprio(1);
  #pragma unroll
  for (int ks = 0; ks < 12; ++ks) {
    bf16x8 bq;
    if constexpr (MODE == 2) {
      // single coalesced 1KB wave-load from the packed fragment table
      bq = *(const bf16x8*)(bp + ((size_t)(w * 12 + ks) * 64 + l) * 8);
    } else {
      const int k  = ks * 32 + ((l >> 4) << 3);
      const int gg = k >> 7;
      const int c  = k & 127;
      const float* wsel = (gg == 0) ? w0 : ((gg == 1) ? w1 : w2);
      const float* wp = wsel + oc * 128 + c;
      f32x4 blo = *(const f32x4*)(wp);
      f32x4 bhi = *(const f32x4*)(wp + 4);
      bq[0]=(__bf16)blo[0]; bq[1]=(__bf16)blo[1]; bq[2]=(__bf16)blo[2]; bq[3]=(__bf16)blo[3];
      bq[4]=(__bf16)bhi[0]; bq[5]=(__bf16)bhi[1]; bq[6]=(__bf16)bhi[2]; bq[7]=(__bf16)bhi[3];
    }

    bf16x8 af[4];
    #pragma unroll
    for (int mt = 0; mt < 4; ++mt) {
      const unsigned row = (unsigned)(mt * 16 + (l & 15));
      unsigned off = row * ROWB + (unsigned)((ks * 32 + ((l >> 4) << 3)) << 1);
      off ^= (unsigned)((l & 7) << 4);               // row&7 == l&7 here
      af[mt] = *(const bf16x8*)(Gs + off);
    }
    #pragma unroll
    for (int mt = 0; mt < 4; ++mt)
      acc[mt] = __builtin_amdgcn_mfma_f32_16x16x32_bf16(af[mt], bq, acc[mt], 0, 0, 0);
  }
  __builtin_amdgcn_s_setprio(0);

  // ---------- epilogue: LDS-staged, full-line NONTEMPORAL out-stores -------------
  __syncthreads();                                   // all MFMA reads of Gs done
  const float bv = bias[oc];
  #pragma unroll
  for (int mt = 0; mt < 4; ++mt) {
    #pragma unroll
    for (int r = 0; r < 4; ++r) {
      const int row = mt * 16 + ((l >> 4) << 2) + r;       // D: row=(lane>>4)*4+reg
      const unsigned b = ((unsigned)(row * 512 + oc * 4)) ^
                         ((unsigned)(((row >> 2) & 3) << 5));
      *(float*)(Gs + b) = acc[mt][r] + bv;                 // D: col=lane&15
    }
  }
  __syncthreads();
  #pragma unroll
  for (int i = 0; i < 4; ++i) {
    const int flat = i * 512 + tid;                  // 2048 x 16B = 64 rows x 512B
    const int row  = flat >> 5;
    const int c16  = flat & 31;
    const unsigned lb = ((unsigned)(row * 512 + c16 * 16)) ^
                        ((unsigned)(((row >> 2) & 3) << 5));
    f32x4 v = *(const f32x4*)(Gs + lb);
    __builtin_nontemporal_store(v, (f32x4*)(out + (size_t)(m0 + row) * 128 + c16 * 4));
  }
}

extern "C" void kernel_launch(void* const* d_in, const int* in_sizes, int n_in,
                              void* d_out, int out_size, void* d_ws, size_t ws_size,
                              hipStream_t stream) {
  const float* x    = (const float*)d_in[0];
  const float* w0   = (const float*)d_in[1];
  const float* w1   = (const float*)d_in[2];
  const float* w2   = (const float*)d_in[3];
  const float* bias = (const float*)d_in[4];
  const int*   fn   = (const int*)d_in[5];
  float* out = (float*)d_out;

  const int n_real = in_sizes[0] / 128;           // 262144
  const int grid   = n_real / BM;                 // 4096 blocks, 512 thr (8 waves)
  const size_t tabB  = (size_t)(n_real + 1) * 128 * sizeof(__bf16); // 67MB + pad row
  const size_t bpOff = (tabB + 1023) & ~(size_t)1023;
  const size_t bpB   = (size_t)8 * 12 * 64 * 8 * sizeof(__bf16);    // 96 KB
  const size_t need1 = (size_t)n_real * 128 * sizeof(__bf16);
  const int cgrid = (n_real * 128) / (256 * 8);   // 16384

  if (ws_size >= bpOff + bpB) {
    __bf16* xtab = (__bf16*)d_ws;
    __bf16* bpp  = (__bf16*)((char*)d_ws + bpOff);
    cvt_bf16<<<cgrid, 256, 0, stream>>>(x, xtab);
    wpack<<<24, 256, 0, stream>>>(w0, w1, w2, bpp, xtab, n_real);
    sfc_main<2><<<grid, 512, 0, stream>>>(xtab, w0, w1, w2, bias, fn, bpp, out, n_real);
  } else if (ws_size >= need1) {
    __bf16* xtab = (__bf16*)d_ws;
    cvt_bf16<<<cgrid, 256, 0, stream>>>(x, xtab);
    sfc_main<1><<<grid, 512, 0, stream>>>(xtab, w0, w1, w2, bias, fn, nullptr, out, n_real);
  } else {
    sfc_main<0><<<grid, 512, 0, stream>>>(x, w0, w1, w2, bias, fn, nullptr, out, n_real);
  }
}